// Round 2
// baseline (1817.872 us; speedup 1.0000x reference)
//
#include <hip/hip_runtime.h>

#define EPSB 1e-5f
#define NEG 0.2f

__device__ __forceinline__ float lrelu(float y) { return y >= 0.f ? y : NEG * y; }

// ---------------------------------------------------------------------------
// Fused conv frontend (unchanged from R1): conv1->conv2->conv3->concat->1x1,
// BN+LReLU each stage, output transposed xt[p][b][s], p<1287,b<32,s<32.
// ---------------------------------------------------------------------------
__global__ __launch_bounds__(256) void k_front(
    const float* __restrict__ data, const float* __restrict__ w1,
    const float* __restrict__ w2, const float* __restrict__ w3,
    const float* __restrict__ lw, const float* __restrict__ bg,
    const float* __restrict__ bb, const float* __restrict__ bm,
    const float* __restrict__ bv, float* __restrict__ xt)
{
  __shared__ float x1s[32][132];
  __shared__ float x2s[32][40];
  __shared__ float x3s[32][20];
  const int b = blockIdx.x >> 3, q = blockIdx.x & 7, t = threadIdx.x;
  const int o1s = (937*q)/8, o1e = (937*(q+1))/8;
  const int o2s = (234*q)/8, o2e = (234*(q+1))/8;
  const int o3s = (116*q)/8, o3e = (116*(q+1))/8;
  int n2s = min(o2s, 2*o3s);
  int n2e = max(o2e, 2*(o3e-1)+4); if (n2e > 234) n2e = 234;
  int n1s = min(o1s, 4*n2s);
  int n1e = max(o1e, 4*(n2e-1)+5); if (n1e > 937) n1e = 937;
  const int w1w = n1e - n1s, w2w = n2e - n2s, w3w = o3e - o3s;

  for (int idx = t; idx < 32*w1w; idx += 256) {
    int c = idx / w1w, j = n1s + idx % w1w;
    float acc = 0.f;
    int base = 5*j - 2;
    #pragma unroll
    for (int k = 0; k < 5; ++k) {
      int pos = base + k;
      float d = (pos >= 0 && pos < 4681) ? data[b*4681 + pos] : 0.f;
      acc += w1[c*5 + k] * d;
    }
    float sc = bg[c] * rsqrtf(bv[c] + EPSB);
    x1s[c][j - n1s] = lrelu((acc - bm[c]) * sc + bb[c]);
  }
  __syncthreads();
  for (int idx = t; idx < 32*w2w; idx += 256) {
    int c = idx / w2w, j = n2s + idx % w2w;
    float acc = 0.f;
    int col = 4*j - n1s;
    for (int ci = 0; ci < 32; ++ci) {
      #pragma unroll
      for (int k = 0; k < 5; ++k) acc += w2[(c*32 + ci)*5 + k] * x1s[ci][col + k];
    }
    float sc = bg[32+c] * rsqrtf(bv[32+c] + EPSB);
    x2s[c][j - n2s] = lrelu((acc - bm[32+c]) * sc + bb[32+c]);
  }
  __syncthreads();
  for (int idx = t; idx < 32*w3w; idx += 256) {
    int c = idx / w3w, j = o3s + idx % w3w;
    float acc = 0.f;
    int col = 2*j - n2s;
    for (int ci = 0; ci < 32; ++ci) {
      #pragma unroll
      for (int k = 0; k < 4; ++k) acc += w3[(c*32 + ci)*4 + k] * x2s[ci][col + k];
    }
    float sc = bg[64+c] * rsqrtf(bv[64+c] + EPSB);
    x3s[c][j - o3s] = lrelu((acc - bm[64+c]) * sc + bb[64+c]);
  }
  __syncthreads();
  const int np1 = o1e - o1s, np2 = o2e - o2s, np3 = o3e - o3s;
  const int np = np1 + np2 + np3;
  for (int idx = t; idx < np*32; idx += 256) {
    int pi = idx >> 5, s = idx & 31;
    float acc = 0.f;
    int p;
    if (pi < np1) {
      int j = o1s + pi; p = j;
      int col = j - n1s;
      for (int ci = 0; ci < 32; ++ci) acc += lw[s*32 + ci] * x1s[ci][col];
    } else if (pi < np1 + np2) {
      int j = o2s + (pi - np1); p = 937 + j;
      int col = j - n2s;
      for (int ci = 0; ci < 32; ++ci) acc += lw[s*32 + ci] * x2s[ci][col];
    } else {
      int j = o3s + (pi - np1 - np2); p = 1171 + j;
      int col = j - o3s;
      for (int ci = 0; ci < 32; ++ci) acc += lw[s*32 + ci] * x3s[ci][col];
    }
    float sc = bg[96+s] * rsqrtf(bv[96+s] + EPSB);
    xt[p*1024 + b*32 + s] = lrelu((acc - bm[96+s]) * sc + bb[96+s]);
  }
}

// ---------------------------------------------------------------------------
// Pass A: u[q4][p][l][v][b4] = sum_s W[l,p,v,s] * x[b,p,s]   (q4=b>>2, b4=b&3)
// + atomic s0[l][v][b] = sum_p u.  One wave per (l, 8-p chunk).
// lane = vg*8+bg: vg -> 5 v's, bg -> b-quad (q4=bg).
// ---------------------------------------------------------------------------
__global__ __launch_bounds__(256) void k_uhat(
    const float* __restrict__ W, const float* __restrict__ xt,
    float* __restrict__ u, float* __restrict__ s0)
{
  const int wi = blockIdx.x*4 + (threadIdx.x >> 6);
  const int lane = threadIdx.x & 63;
  const int l = wi % 40, chunk = wi / 40;
  const int vg = lane >> 3, bg = lane & 7;
  const int p0 = chunk * 8;
  float s0acc[5][4] = {};
  for (int pp = 0; pp < 8; ++pp) {
    int p = p0 + pp;
    if (p >= 1287) break;
    const float* Wt = W + (size_t)(l*1287 + p) * 1280;  // [v][s]
    const float* xp = xt + p*1024;                      // [b][s]
    float acc[5][4] = {};
    #pragma unroll 2
    for (int s4 = 0; s4 < 8; ++s4) {
      float4 wv[5], xv[4];
      #pragma unroll
      for (int i = 0; i < 5; ++i) wv[i] = *(const float4*)(Wt + (vg*5 + i)*32 + s4*4);
      #pragma unroll
      for (int j = 0; j < 4; ++j) xv[j] = *(const float4*)(xp + (bg*4 + j)*32 + s4*4);
      #pragma unroll
      for (int i = 0; i < 5; ++i)
        #pragma unroll
        for (int j = 0; j < 4; ++j)
          acc[i][j] += wv[i].x*xv[j].x + wv[i].y*xv[j].y + wv[i].z*xv[j].z + wv[i].w*xv[j].w;
    }
    // slab word index = (l*40+v)*4 + b4
    float* up = u + ((size_t)(bg*1287 + p))*6400 + l*160;
    #pragma unroll
    for (int i = 0; i < 5; ++i) {
      int v = vg*5 + i;
      *(float4*)(up + v*4) = make_float4(acc[i][0], acc[i][1], acc[i][2], acc[i][3]);
      #pragma unroll
      for (int j = 0; j < 4; ++j) s0acc[i][j] += acc[i][j];
    }
  }
  #pragma unroll
  for (int i = 0; i < 5; ++i) {
    int v = vg*5 + i;
    #pragma unroll
    for (int j = 0; j < 4; ++j)
      atomicAdd(&s0[(l*40 + v)*32 + bg*4 + j], s0acc[i][j]);
  }
}

// ---------------------------------------------------------------------------
// squash0: s0 [lv][b32] -> v0t [q4][lv][b4], scaled by 1/40 (uniform c).
// block per (b,l), 64 threads, t = v.
// ---------------------------------------------------------------------------
__global__ __launch_bounds__(64) void k_squash0(
    const float* __restrict__ s0, float* __restrict__ v0t)
{
  const int b = blockIdx.x / 40, l = blockIdx.x % 40, t = threadIdx.x;
  float s = 0.f;
  if (t < 40) s = s0[(l*40 + t)*32 + b] * (1.f/40.f);
  float sq = s*s;
  #pragma unroll
  for (int d = 1; d < 64; d <<= 1) sq += __shfl_xor(sq, d);
  float scale = sq > 0.f ? sq / ((1.f + sq) * sqrtf(sq)) : 0.f;
  if (t < 40) v0t[((size_t)(b >> 2)*1600 + l*40 + t)*4 + (b & 3)] = s * scale;
}

// squash1: sred [q4][lv][b4] -> v1t same layout (no 1/40 scale).
__global__ __launch_bounds__(64) void k_squash1(
    const float* __restrict__ sred, float* __restrict__ v1t)
{
  const int b = blockIdx.x / 40, l = blockIdx.x % 40, t = threadIdx.x;
  float s = 0.f;
  size_t off = ((size_t)(b >> 2)*1600 + l*40 + t)*4 + (b & 3);
  if (t < 40) s = sred[off];
  float sq = s*s;
  #pragma unroll
  for (int d = 1; d < 64; d <<= 1) sq += __shfl_xor(sq, d);
  float scale = sq > 0.f ? sq / ((1.f + sq) * sqrtf(sq)) : 0.f;
  if (t < 40) v1t[off] = s * scale;
}

__global__ __launch_bounds__(64) void k_final(
    const float* __restrict__ sred, float* __restrict__ out)
{
  const int b = blockIdx.x / 40, l = blockIdx.x % 40, t = threadIdx.x;
  float s = 0.f;
  if (t < 40) s = sred[((size_t)(b >> 2)*1600 + l*40 + t)*4 + (b & 3)];
  float sq = s*s, ss = s;
  #pragma unroll
  for (int d = 1; d < 64; d <<= 1) { sq += __shfl_xor(sq, d); ss += __shfl_xor(ss, d); }
  float scale = sq > 0.f ? sq / ((1.f + sq) * sqrtf(sq)) : 0.f;
  if (t == 0) out[b*40 + l] = ss * scale;
}

// ---------------------------------------------------------------------------
// coalesced partial-sum reduce: sout[w] = sum_c spart[c][w], w < 51200.
// ---------------------------------------------------------------------------
__global__ __launch_bounds__(256) void k_reduce(
    const float* __restrict__ spart, float* __restrict__ sout)
{
  const int w = blockIdx.x*256 + threadIdx.x;
  float s = 0.f;
  for (int c = 0; c < 129; ++c) s += spart[(size_t)c*51200 + w];
  sout[w] = s;
}

// ---------------------------------------------------------------------------
// Routing pass. Block = (q4 = b-quad, chunk of PC p's), 320 threads.
// Per p: load u slab (1600 float4) into REGISTERS (5 float4/thread,
// lane-contiguous = perfectly coalesced), dot-reduce via LDS atomics,
// softmax over l (t<4, one per b), s += c*u from regs.
// Thread t owns float4 slab indices f = k*320+t (k<5); l(f) = 8k + t/40.
// ---------------------------------------------------------------------------
#define PC 10
__global__ __launch_bounds__(320) void k_route(
    const float* __restrict__ u, const float* __restrict__ vprev,
    float* __restrict__ b1g, float* __restrict__ spart, int pass)
{
  __shared__ float dot_lds[160];
  __shared__ float c_lds[160];
  const int q4 = blockIdx.x & 7, chunk = blockIdx.x >> 3;
  const int t = threadIdx.x;
  const int lq = t / 40;                 // l offset within k-slab
  float sreg[5][4] = {};
  const int p0 = chunk * PC;
  const float* vp = vprev + (size_t)q4 * 6400;
  for (int pp = 0; pp < PC; ++pp) {
    int p = p0 + pp;
    if (p >= 1287) break;
    const size_t pb = (size_t)q4*1287 + p;
    if (t < 160) dot_lds[t] = (pass == 1) ? 0.f : b1g[pb*160 + t];
    __syncthreads();
    const float* up = u + pb * 6400;
    float4 uu[5];
    #pragma unroll
    for (int k = 0; k < 5; ++k) uu[k] = *(const float4*)(up + (k*320 + t)*4);
    #pragma unroll
    for (int k = 0; k < 5; ++k) {
      float4 vv = *(const float4*)(vp + (k*320 + t)*4);
      int dl = (8*k + lq)*4;
      atomicAdd(&dot_lds[dl + 0], uu[k].x*vv.x);
      atomicAdd(&dot_lds[dl + 1], uu[k].y*vv.y);
      atomicAdd(&dot_lds[dl + 2], uu[k].z*vv.z);
      atomicAdd(&dot_lds[dl + 3], uu[k].w*vv.w);
    }
    __syncthreads();
    if (t < 4) {
      float m = -1e30f;
      for (int li = 0; li < 40; ++li) m = fmaxf(m, dot_lds[li*4 + t]);
      float Z = 0.f;
      for (int li = 0; li < 40; ++li) {
        float e = expf(dot_lds[li*4 + t] - m);
        c_lds[li*4 + t] = e; Z += e;
      }
      float r = 1.f / Z;
      for (int li = 0; li < 40; ++li) c_lds[li*4 + t] *= r;
    }
    if (pass == 1 && t < 160) b1g[pb*160 + t] = dot_lds[t];
    __syncthreads();
    #pragma unroll
    for (int k = 0; k < 5; ++k) {
      float4 cc = *(const float4*)(&c_lds[(8*k + lq)*4]);
      sreg[k][0] += uu[k].x*cc.x; sreg[k][1] += uu[k].y*cc.y;
      sreg[k][2] += uu[k].z*cc.z; sreg[k][3] += uu[k].w*cc.w;
    }
  }
  float* sp = spart + ((size_t)chunk*8 + q4) * 6400;
  #pragma unroll
  for (int k = 0; k < 5; ++k)
    *(float4*)(sp + (k*320 + t)*4) =
        make_float4(sreg[k][0], sreg[k][1], sreg[k][2], sreg[k][3]);
}

// ---------------------------------------------------------------------------
extern "C" void kernel_launch(void* const* d_in, const int* in_sizes, int n_in,
                              void* d_out, int out_size, void* d_ws, size_t ws_size,
                              hipStream_t stream)
{
  const float* data = (const float*)d_in[0];
  const float* w1   = (const float*)d_in[1];
  const float* w2   = (const float*)d_in[2];
  const float* w3   = (const float*)d_in[3];
  const float* lw   = (const float*)d_in[4];
  const float* bg   = (const float*)d_in[5];
  const float* bb   = (const float*)d_in[6];
  const float* bm   = (const float*)d_in[7];
  const float* bv   = (const float*)d_in[8];
  const float* W    = (const float*)d_in[9];
  float* out = (float*)d_out;

  float* xt    = (float*)d_ws;              // 1,317,888 words
  float* u     = xt + 1317888;              // 65,894,400 words
  float* s0    = u + 65894400;              // 51,200  (later reused as s2)
  float* v0t   = s0 + 51200;                // 51,200  (later reused as s1)
  float* v1t   = v0t + 51200;               // 51,200
  float* b1g   = v1t + 51200;               // 1,647,360
  float* spart = b1g + 1647360;             // 6,604,800
  // total ~302.5 MB of workspace

  hipMemsetAsync(s0, 0, 51200 * sizeof(float), stream);
  k_front<<<256, 256, 0, stream>>>(data, w1, w2, w3, lw, bg, bb, bm, bv, xt);
  k_uhat<<<1610, 256, 0, stream>>>(W, xt, u, s0);
  k_squash0<<<1280, 64, 0, stream>>>(s0, v0t);
  k_route<<<1032, 320, 0, stream>>>(u, v0t, b1g, spart, 1);
  k_reduce<<<200, 256, 0, stream>>>(spart, v0t);          // s1 -> reuse v0t
  k_squash1<<<1280, 64, 0, stream>>>(v0t, v1t);
  k_route<<<1032, 320, 0, stream>>>(u, v1t, b1g, spart, 2);
  k_reduce<<<200, 256, 0, stream>>>(spart, s0);           // s2 -> reuse s0
  k_final<<<1280, 64, 0, stream>>>(s0, out);
}

// Round 3
// 804.876 us; speedup vs baseline: 2.2586x; 2.2586x over previous
//
#include <hip/hip_runtime.h>

#define EPSB 1e-5f
#define NEG 0.2f

__device__ __forceinline__ float lrelu(float y) { return y >= 0.f ? y : NEG * y; }

// ---------------------------------------------------------------------------
// Fused conv frontend (unchanged): conv1->conv2->conv3->concat->1x1,
// BN+LReLU each stage, output transposed xt[p][b][s], p<1287,b<32,s<32.
// ---------------------------------------------------------------------------
__global__ __launch_bounds__(256) void k_front(
    const float* __restrict__ data, const float* __restrict__ w1,
    const float* __restrict__ w2, const float* __restrict__ w3,
    const float* __restrict__ lw, const float* __restrict__ bg,
    const float* __restrict__ bb, const float* __restrict__ bm,
    const float* __restrict__ bv, float* __restrict__ xt)
{
  __shared__ float x1s[32][132];
  __shared__ float x2s[32][40];
  __shared__ float x3s[32][20];
  const int b = blockIdx.x >> 3, q = blockIdx.x & 7, t = threadIdx.x;
  const int o1s = (937*q)/8, o1e = (937*(q+1))/8;
  const int o2s = (234*q)/8, o2e = (234*(q+1))/8;
  const int o3s = (116*q)/8, o3e = (116*(q+1))/8;
  int n2s = min(o2s, 2*o3s);
  int n2e = max(o2e, 2*(o3e-1)+4); if (n2e > 234) n2e = 234;
  int n1s = min(o1s, 4*n2s);
  int n1e = max(o1e, 4*(n2e-1)+5); if (n1e > 937) n1e = 937;
  const int w1w = n1e - n1s, w2w = n2e - n2s, w3w = o3e - o3s;

  for (int idx = t; idx < 32*w1w; idx += 256) {
    int c = idx / w1w, j = n1s + idx % w1w;
    float acc = 0.f;
    int base = 5*j - 2;
    #pragma unroll
    for (int k = 0; k < 5; ++k) {
      int pos = base + k;
      float d = (pos >= 0 && pos < 4681) ? data[b*4681 + pos] : 0.f;
      acc += w1[c*5 + k] * d;
    }
    float sc = bg[c] * rsqrtf(bv[c] + EPSB);
    x1s[c][j - n1s] = lrelu((acc - bm[c]) * sc + bb[c]);
  }
  __syncthreads();
  for (int idx = t; idx < 32*w2w; idx += 256) {
    int c = idx / w2w, j = n2s + idx % w2w;
    float acc = 0.f;
    int col = 4*j - n1s;
    for (int ci = 0; ci < 32; ++ci) {
      #pragma unroll
      for (int k = 0; k < 5; ++k) acc += w2[(c*32 + ci)*5 + k] * x1s[ci][col + k];
    }
    float sc = bg[32+c] * rsqrtf(bv[32+c] + EPSB);
    x2s[c][j - n2s] = lrelu((acc - bm[32+c]) * sc + bb[32+c]);
  }
  __syncthreads();
  for (int idx = t; idx < 32*w3w; idx += 256) {
    int c = idx / w3w, j = o3s + idx % w3w;
    float acc = 0.f;
    int col = 2*j - n2s;
    for (int ci = 0; ci < 32; ++ci) {
      #pragma unroll
      for (int k = 0; k < 4; ++k) acc += w3[(c*32 + ci)*4 + k] * x2s[ci][col + k];
    }
    float sc = bg[64+c] * rsqrtf(bv[64+c] + EPSB);
    x3s[c][j - o3s] = lrelu((acc - bm[64+c]) * sc + bb[64+c]);
  }
  __syncthreads();
  const int np1 = o1e - o1s, np2 = o2e - o2s, np3 = o3e - o3s;
  const int np = np1 + np2 + np3;
  for (int idx = t; idx < np*32; idx += 256) {
    int pi = idx >> 5, s = idx & 31;
    float acc = 0.f;
    int p;
    if (pi < np1) {
      int j = o1s + pi; p = j;
      int col = j - n1s;
      for (int ci = 0; ci < 32; ++ci) acc += lw[s*32 + ci] * x1s[ci][col];
    } else if (pi < np1 + np2) {
      int j = o2s + (pi - np1); p = 937 + j;
      int col = j - n2s;
      for (int ci = 0; ci < 32; ++ci) acc += lw[s*32 + ci] * x2s[ci][col];
    } else {
      int j = o3s + (pi - np1 - np2); p = 1171 + j;
      int col = j - o3s;
      for (int ci = 0; ci < 32; ++ci) acc += lw[s*32 + ci] * x3s[ci][col];
    }
    float sc = bg[96+s] * rsqrtf(bv[96+s] + EPSB);
    xt[p*1024 + b*32 + s] = lrelu((acc - bm[96+s]) * sc + bb[96+s]);
  }
}

// ---------------------------------------------------------------------------
// Pass A (unchanged control): u[q4][p][l][v][b4] = sum_s W[l,p,v,s] x[b,p,s]
// + atomic s0[l][v][b32] = sum_p u.  One wave per (l, 8-p chunk).
// ---------------------------------------------------------------------------
__global__ __launch_bounds__(256) void k_uhat(
    const float* __restrict__ W, const float* __restrict__ xt,
    float* __restrict__ u, float* __restrict__ s0)
{
  const int wi = blockIdx.x*4 + (threadIdx.x >> 6);
  const int lane = threadIdx.x & 63;
  const int l = wi % 40, chunk = wi / 40;
  const int vg = lane >> 3, bg = lane & 7;
  const int p0 = chunk * 8;
  float s0acc[5][4] = {};
  for (int pp = 0; pp < 8; ++pp) {
    int p = p0 + pp;
    if (p >= 1287) break;
    const float* Wt = W + (size_t)(l*1287 + p) * 1280;  // [v][s]
    const float* xp = xt + p*1024;                      // [b][s]
    float acc[5][4] = {};
    #pragma unroll 2
    for (int s4 = 0; s4 < 8; ++s4) {
      float4 wv[5], xv[4];
      #pragma unroll
      for (int i = 0; i < 5; ++i) wv[i] = *(const float4*)(Wt + (vg*5 + i)*32 + s4*4);
      #pragma unroll
      for (int j = 0; j < 4; ++j) xv[j] = *(const float4*)(xp + (bg*4 + j)*32 + s4*4);
      #pragma unroll
      for (int i = 0; i < 5; ++i)
        #pragma unroll
        for (int j = 0; j < 4; ++j)
          acc[i][j] += wv[i].x*xv[j].x + wv[i].y*xv[j].y + wv[i].z*xv[j].z + wv[i].w*xv[j].w;
    }
    float* up = u + ((size_t)(bg*1287 + p))*6400 + l*160;
    #pragma unroll
    for (int i = 0; i < 5; ++i) {
      int v = vg*5 + i;
      *(float4*)(up + v*4) = make_float4(acc[i][0], acc[i][1], acc[i][2], acc[i][3]);
      #pragma unroll
      for (int j = 0; j < 4; ++j) s0acc[i][j] += acc[i][j];
    }
  }
  #pragma unroll
  for (int i = 0; i < 5; ++i) {
    int v = vg*5 + i;
    #pragma unroll
    for (int j = 0; j < 4; ++j)
      atomicAdd(&s0[(l*40 + v)*32 + bg*4 + j], s0acc[i][j]);
  }
}

// ---------------------------------------------------------------------------
// squash0: s0 [lv][b32] -> v0t [q4][l][v][b4], scaled by 1/40 (uniform c).
// ---------------------------------------------------------------------------
__global__ __launch_bounds__(64) void k_squash0(
    const float* __restrict__ s0, float* __restrict__ v0t)
{
  const int b = blockIdx.x / 40, l = blockIdx.x % 40, t = threadIdx.x;
  float s = 0.f;
  if (t < 40) s = s0[(l*40 + t)*32 + b] * (1.f/40.f);
  float sq = s*s;
  #pragma unroll
  for (int d = 1; d < 64; d <<= 1) sq += __shfl_xor(sq, d);
  float scale = sq > 0.f ? sq / ((1.f + sq) * sqrtf(sq)) : 0.f;
  if (t < 40) v0t[((size_t)(b >> 2)*1600 + l*40 + t)*4 + (b & 3)] = s * scale;
}

__global__ __launch_bounds__(64) void k_squash1(
    const float* __restrict__ sred, float* __restrict__ v1t)
{
  const int b = blockIdx.x / 40, l = blockIdx.x % 40, t = threadIdx.x;
  float s = 0.f;
  size_t off = ((size_t)(b >> 2)*1600 + l*40 + t)*4 + (b & 3);
  if (t < 40) s = sred[off];
  float sq = s*s;
  #pragma unroll
  for (int d = 1; d < 64; d <<= 1) sq += __shfl_xor(sq, d);
  float scale = sq > 0.f ? sq / ((1.f + sq) * sqrtf(sq)) : 0.f;
  if (t < 40) v1t[off] = s * scale;
}

__global__ __launch_bounds__(64) void k_final(
    const float* __restrict__ sred, float* __restrict__ out)
{
  const int b = blockIdx.x / 40, l = blockIdx.x % 40, t = threadIdx.x;
  float s = 0.f;
  if (t < 40) s = sred[((size_t)(b >> 2)*1600 + l*40 + t)*4 + (b & 3)];
  float sq = s*s, ss = s;
  #pragma unroll
  for (int d = 1; d < 64; d <<= 1) { sq += __shfl_xor(sq, d); ss += __shfl_xor(ss, d); }
  float scale = sq > 0.f ? sq / ((1.f + sq) * sqrtf(sq)) : 0.f;
  if (t == 0) out[b*40 + l] = ss * scale;
}

// ---------------------------------------------------------------------------
// k_dot: b_ij logits. Thread = (q4,p,l); reads its CONTIGUOUS 640B u-run
// (40 float4, components = 4 b's) + matching vprev run; float4 dot; writes
// b1g[tid*4..+3] (float4). pass2 accumulates onto stored pass-1 logits.
// ---------------------------------------------------------------------------
__global__ __launch_bounds__(256) void k_dot(
    const float* __restrict__ u, const float* __restrict__ vprev,
    float* __restrict__ b1g, int pass)
{
  const int tid = blockIdx.x*256 + threadIdx.x;   // (q4*1287 + p)*40 + l
  if (tid >= 411840) return;
  const int l = tid % 40;
  const int y = tid / 40;
  const int p = y % 1287, q4 = y / 1287;
  const float4* up = (const float4*)(u + (size_t)(q4*1287 + p)*6400 + l*160);
  const float4* vp = (const float4*)(vprev + ((size_t)q4*1600 + l*40)*4);
  float4 d = make_float4(0.f, 0.f, 0.f, 0.f);
  #pragma unroll 8
  for (int v = 0; v < 40; ++v) {
    float4 uu = up[v], vv = vp[v];
    d.x += uu.x*vv.x; d.y += uu.y*vv.y; d.z += uu.z*vv.z; d.w += uu.w*vv.w;
  }
  float4* bp = (float4*)(b1g + (size_t)tid*4);
  if (pass == 2) {
    float4 o = *bp;
    d.x += o.x; d.y += o.y; d.z += o.z; d.w += o.w;
  }
  *bp = d;
}

// ---------------------------------------------------------------------------
// k_soft: softmax over l per (b,p). Thread = (q4,p,b4); 40 strided reads of
// L2-hot b1g; writes c_g (b1g kept raw for pass-2 accumulation).
// ---------------------------------------------------------------------------
__global__ __launch_bounds__(256) void k_soft(
    const float* __restrict__ b1g, float* __restrict__ c_g)
{
  const int tid = blockIdx.x*256 + threadIdx.x;   // (q4*1287+p)*4 + b4
  if (tid >= 41184) return;
  const int b4 = tid & 3, qp = tid >> 2;
  const float* base = b1g + (size_t)qp*160 + b4;
  float e[40];
  float m = -1e30f;
  #pragma unroll
  for (int li = 0; li < 40; ++li) { e[li] = base[li*4]; m = fmaxf(m, e[li]); }
  float Z = 0.f;
  #pragma unroll
  for (int li = 0; li < 40; ++li) { e[li] = expf(e[li] - m); Z += e[li]; }
  float r = 1.f / Z;
  float* cb = c_g + (size_t)qp*160 + b4;
  #pragma unroll
  for (int li = 0; li < 40; ++li) cb[li*4] = e[li] * r;
}

// ---------------------------------------------------------------------------
// k_sacc: s partials = sum_p c*u. Block = (q4, chunk of PC p's), 320 thr.
// Per p: 5 fully-coalesced u float4 + broadcast c float4 per l. No LDS,
// no barriers, no atomics. Writes spart[chunk*8+q4][6400].
// ---------------------------------------------------------------------------
#define PC 10
__global__ __launch_bounds__(320) void k_sacc(
    const float* __restrict__ u, const float* __restrict__ c_g,
    float* __restrict__ spart)
{
  const int q4 = blockIdx.x & 7, chunk = blockIdx.x >> 3;
  const int t = threadIdx.x;
  float4 sreg[5];
  int l4[5];
  #pragma unroll
  for (int k = 0; k < 5; ++k) {
    sreg[k] = make_float4(0.f, 0.f, 0.f, 0.f);
    l4[k] = (k*320 + t) / 40;          // l of float4 f = k*320+t
  }
  const int p0 = chunk * PC;
  #pragma unroll 2
  for (int pp = 0; pp < PC; ++pp) {
    int p = p0 + pp;
    if (p >= 1287) break;
    const float4* up = (const float4*)(u + (size_t)(q4*1287 + p)*6400);
    const float4* cp = (const float4*)(c_g + (size_t)(q4*1287 + p)*160);
    #pragma unroll
    for (int k = 0; k < 5; ++k) {
      float4 uu = up[k*320 + t];
      float4 cc = cp[l4[k]];
      sreg[k].x += uu.x*cc.x; sreg[k].y += uu.y*cc.y;
      sreg[k].z += uu.z*cc.z; sreg[k].w += uu.w*cc.w;
    }
  }
  float4* sp = (float4*)(spart + ((size_t)chunk*8 + q4)*6400);
  #pragma unroll
  for (int k = 0; k < 5; ++k) sp[k*320 + t] = sreg[k];
}

// ---------------------------------------------------------------------------
// coalesced partial-sum reduce: sout[w] = sum_c spart[c][w], w < 51200.
// ---------------------------------------------------------------------------
__global__ __launch_bounds__(256) void k_reduce(
    const float* __restrict__ spart, float* __restrict__ sout)
{
  const int w = blockIdx.x*256 + threadIdx.x;
  float s = 0.f;
  #pragma unroll 4
  for (int c = 0; c < 129; ++c) s += spart[(size_t)c*51200 + w];
  sout[w] = s;
}

// ---------------------------------------------------------------------------
extern "C" void kernel_launch(void* const* d_in, const int* in_sizes, int n_in,
                              void* d_out, int out_size, void* d_ws, size_t ws_size,
                              hipStream_t stream)
{
  const float* data = (const float*)d_in[0];
  const float* w1   = (const float*)d_in[1];
  const float* w2   = (const float*)d_in[2];
  const float* w3   = (const float*)d_in[3];
  const float* lw   = (const float*)d_in[4];
  const float* bg   = (const float*)d_in[5];
  const float* bb   = (const float*)d_in[6];
  const float* bm   = (const float*)d_in[7];
  const float* bv   = (const float*)d_in[8];
  const float* W    = (const float*)d_in[9];
  float* out = (float*)d_out;

  float* u     = (float*)d_ws;              // 65,894,400 words
  float* s0    = u + 65894400;              // 51,200 (reused as s2 target)
  float* v0t   = s0 + 51200;                // 51,200
  float* v1t   = v0t + 51200;               // 51,200
  float* s1    = v1t + 51200;               // 51,200
  float* b1g   = s1 + 51200;                // 1,647,360
  float* c_g   = b1g + 1647360;             // 1,647,360
  float* spart = c_g + 1647360;             // 6,604,800
  float* xt    = spart;                     // alias: xt dead before k_sacc runs
  // total ~304 MB of workspace

  hipMemsetAsync(s0, 0, 51200 * sizeof(float), stream);
  k_front<<<256, 256, 0, stream>>>(data, w1, w2, w3, lw, bg, bb, bm, bv, xt);
  k_uhat<<<1610, 256, 0, stream>>>(W, xt, u, s0);
  k_squash0<<<1280, 64, 0, stream>>>(s0, v0t);

  k_dot<<<1609, 256, 0, stream>>>(u, v0t, b1g, 1);
  k_soft<<<161, 256, 0, stream>>>(b1g, c_g);
  k_sacc<<<1032, 320, 0, stream>>>(u, c_g, spart);
  k_reduce<<<200, 256, 0, stream>>>(spart, s1);
  k_squash1<<<1280, 64, 0, stream>>>(s1, v1t);

  k_dot<<<1609, 256, 0, stream>>>(u, v1t, b1g, 2);
  k_soft<<<161, 256, 0, stream>>>(b1g, c_g);
  k_sacc<<<1032, 320, 0, stream>>>(u, c_g, spart);
  k_reduce<<<200, 256, 0, stream>>>(spart, s0);
  k_final<<<1280, 64, 0, stream>>>(s0, out);
}

// Round 4
// 592.517 us; speedup vs baseline: 3.0681x; 1.3584x over previous
//
#include <hip/hip_runtime.h>

#define EPSB 1e-5f
#define NEG 0.2f

__device__ __forceinline__ float lrelu(float y) { return y >= 0.f ? y : NEG * y; }

// async global->LDS 16B/lane (wave-uniform LDS dest, per-lane global src)
typedef const __attribute__((address_space(1))) unsigned int gas1_u32;
typedef __attribute__((address_space(3))) unsigned int as3_u32;
__device__ __forceinline__ void gload16(const float* g, float* l) {
  __builtin_amdgcn_global_load_lds((gas1_u32*)g, (as3_u32*)l, 16, 0, 0);
}
#define WAITVM(N) asm volatile("s_waitcnt vmcnt(" #N ")" ::: "memory")

// ---------------------------------------------------------------------------
// Fused conv frontend (unchanged, validated): output xt[p][b][s].
// ---------------------------------------------------------------------------
__global__ __launch_bounds__(256) void k_front(
    const float* __restrict__ data, const float* __restrict__ w1,
    const float* __restrict__ w2, const float* __restrict__ w3,
    const float* __restrict__ lw, const float* __restrict__ bg,
    const float* __restrict__ bb, const float* __restrict__ bm,
    const float* __restrict__ bv, float* __restrict__ xt)
{
  __shared__ float x1s[32][132];
  __shared__ float x2s[32][40];
  __shared__ float x3s[32][20];
  const int b = blockIdx.x >> 3, q = blockIdx.x & 7, t = threadIdx.x;
  const int o1s = (937*q)/8, o1e = (937*(q+1))/8;
  const int o2s = (234*q)/8, o2e = (234*(q+1))/8;
  const int o3s = (116*q)/8, o3e = (116*(q+1))/8;
  int n2s = min(o2s, 2*o3s);
  int n2e = max(o2e, 2*(o3e-1)+4); if (n2e > 234) n2e = 234;
  int n1s = min(o1s, 4*n2s);
  int n1e = max(o1e, 4*(n2e-1)+5); if (n1e > 937) n1e = 937;
  const int w1w = n1e - n1s, w2w = n2e - n2s, w3w = o3e - o3s;

  for (int idx = t; idx < 32*w1w; idx += 256) {
    int c = idx / w1w, j = n1s + idx % w1w;
    float acc = 0.f;
    int base = 5*j - 2;
    #pragma unroll
    for (int k = 0; k < 5; ++k) {
      int pos = base + k;
      float d = (pos >= 0 && pos < 4681) ? data[b*4681 + pos] : 0.f;
      acc += w1[c*5 + k] * d;
    }
    float sc = bg[c] * rsqrtf(bv[c] + EPSB);
    x1s[c][j - n1s] = lrelu((acc - bm[c]) * sc + bb[c]);
  }
  __syncthreads();
  for (int idx = t; idx < 32*w2w; idx += 256) {
    int c = idx / w2w, j = n2s + idx % w2w;
    float acc = 0.f;
    int col = 4*j - n1s;
    for (int ci = 0; ci < 32; ++ci) {
      #pragma unroll
      for (int k = 0; k < 5; ++k) acc += w2[(c*32 + ci)*5 + k] * x1s[ci][col + k];
    }
    float sc = bg[32+c] * rsqrtf(bv[32+c] + EPSB);
    x2s[c][j - n2s] = lrelu((acc - bm[32+c]) * sc + bb[32+c]);
  }
  __syncthreads();
  for (int idx = t; idx < 32*w3w; idx += 256) {
    int c = idx / w3w, j = o3s + idx % w3w;
    float acc = 0.f;
    int col = 2*j - n2s;
    for (int ci = 0; ci < 32; ++ci) {
      #pragma unroll
      for (int k = 0; k < 4; ++k) acc += w3[(c*32 + ci)*4 + k] * x2s[ci][col + k];
    }
    float sc = bg[64+c] * rsqrtf(bv[64+c] + EPSB);
    x3s[c][j - o3s] = lrelu((acc - bm[64+c]) * sc + bb[64+c]);
  }
  __syncthreads();
  const int np1 = o1e - o1s, np2 = o2e - o2s, np3 = o3e - o3s;
  const int np = np1 + np2 + np3;
  for (int idx = t; idx < np*32; idx += 256) {
    int pi = idx >> 5, s = idx & 31;
    float acc = 0.f;
    int p;
    if (pi < np1) {
      int j = o1s + pi; p = j;
      int col = j - n1s;
      for (int ci = 0; ci < 32; ++ci) acc += lw[s*32 + ci] * x1s[ci][col];
    } else if (pi < np1 + np2) {
      int j = o2s + (pi - np1); p = 937 + j;
      int col = j - n2s;
      for (int ci = 0; ci < 32; ++ci) acc += lw[s*32 + ci] * x2s[ci][col];
    } else {
      int j = o3s + (pi - np1 - np2); p = 1171 + j;
      int col = j - o3s;
      for (int ci = 0; ci < 32; ++ci) acc += lw[s*32 + ci] * x3s[ci][col];
    }
    float sc = bg[96+s] * rsqrtf(bv[96+s] + EPSB);
    xt[p*1024 + b*32 + s] = lrelu((acc - bm[96+s]) * sc + bb[96+s]);
  }
}

// ---------------------------------------------------------------------------
// Pass A v2: u[q4][p][l][v][b4] = sum_s W[l,p,v,s] x[b,p,s].
// Wave = (l, chunk of 8 p). W streamed via global_load_lds (5x1KB DMA per
// (l,p), double-buffered per wave, counted vmcnt waits). x staged once per
// block in LDS (all 4 waves share the chunk). XOR bank swizzles on both.
// s0 partials written per chunk (no atomics): s0part[chunk][(l*40+v)*32+b].
// LDS: xs 32KB + 4 waves * 2 * 5KB = 72KB dynamic.
// ---------------------------------------------------------------------------
__global__ __launch_bounds__(256) void k_uhat(
    const float* __restrict__ W, const float* __restrict__ xt,
    float* __restrict__ u, float* __restrict__ s0part)
{
  extern __shared__ float lds[];
  float* xs = lds;                       // [8 p][32 b][32 s] swizzled
  float* wbuf = lds + 8192;              // [4 waves][2][1280]
  const int t = threadIdx.x;
  const int wi = blockIdx.x*4 + (t >> 6);
  const int lane = t & 63;
  const int l = wi % 40, chunk = wi / 40;
  const int vg = lane >> 3, bg = lane & 7;
  const int p0 = chunk * 8;
  float* myw = wbuf + (t >> 6) * 2560;
  const float* Wl = W + (size_t)l * 1287 * 1280;

  // stage x chunk into LDS (swizzled: s4 ^= b>>2), coalesced float4 reads
  for (int g = t; g < 2048; g += 256) {
    int pl = g >> 8, rem = g & 255;
    int b = rem >> 3, s4 = rem & 7;
    int pg = p0 + pl;
    float4 v = make_float4(0.f, 0.f, 0.f, 0.f);
    if (pg < 1287) v = *(const float4*)(xt + pg*1024 + b*32 + s4*4);
    *(float4*)(xs + pl*1024 + b*32 + ((s4 ^ (b >> 2)) << 2)) = v;
  }
  // prologue: stage W(p0) and W(p0+1) into buffers 0,1 (per-wave, no barrier)
  {
    #pragma unroll
    for (int i = 0; i < 5; ++i) {
      int g = i*64 + lane, v = g >> 3, s4 = (g & 7) ^ (v & 7);
      gload16(Wl + (size_t)p0*1280 + (v*8 + s4)*4, myw + i*256);
    }
    if (p0 + 1 < 1287) {
      #pragma unroll
      for (int i = 0; i < 5; ++i) {
        int g = i*64 + lane, v = g >> 3, s4 = (g & 7) ^ (v & 7);
        gload16(Wl + (size_t)(p0+1)*1280 + (v*8 + s4)*4, myw + 1280 + i*256);
      }
    }
  }
  __syncthreads();

  float s0acc[5][4] = {};
  int cur = 0;
  for (int pp = 0; pp < 8; ++pp) {
    int p = p0 + pp;
    if (p >= 1287) break;
    // drain this wave's ds_reads before the DMA below may overwrite nbuf
    asm volatile("s_waitcnt lgkmcnt(0)" ::: "memory");
    bool st = (pp < 7) && (p + 2 < 1288) && (p + 2 < 1287 + 1) && (p + 2 <= 1287) && (p + 2 < 1288);
    st = (pp < 7) && (p + 2 <= 1287) && (p + 2 < 1288) && ((p + 2) < 1287 + 1);
    st = (pp < 7) && (p + 2 < 1288) && (p + 2 - 1 < 1287);   // stage p+2? no:
    // we stage p+2's slot = buffer (cur) after it is consumed... simpler:
    // buffers hold p (cur) and p+1 (cur^1); stage p+2 into cur after compute?
    // To keep one-stage-ahead: stage p+2 into THIS buffer after use is wrong
    // mid-loop. Use: stage p+2 before computing p (into cur's replacement is
    // not free). Instead: prologue staged p0,p1; here stage p+2 into the
    // buffer that held p-? -> stage (p+2) into buffer (pp&1)^0? Buffer of p
    // is cur; it frees after this iteration; p+2 must go into cur, but only
    // after compute. So: stage AFTER compute, wait before next use (2 deep).
    (void)st;
    // wait for buffer cur (p's data): prologue/steady analysis:
    //   outstanding newest ops are at most {stores(<=5), stage issued last}
    if (pp == 0) { WAITVM(5); } else { WAITVM(5); }
    const float* wb = myw + cur*1280;
    const float* xp = xs + pp*1024;
    float acc[5][4] = {};
    #pragma unroll
    for (int s4 = 0; s4 < 8; ++s4) {
      float4 wv[5], xv[4];
      #pragma unroll
      for (int i = 0; i < 5; ++i) {
        int v = vg*5 + i;
        wv[i] = *(const float4*)(wb + v*32 + (((s4 ^ (v & 7))) << 2));
      }
      #pragma unroll
      for (int j = 0; j < 4; ++j) {
        int b = bg*4 + j;
        xv[j] = *(const float4*)(xp + b*32 + ((s4 ^ (b >> 2)) << 2));
      }
      #pragma unroll
      for (int i = 0; i < 5; ++i)
        #pragma unroll
        for (int j = 0; j < 4; ++j)
          acc[i][j] += wv[i].x*xv[j].x + wv[i].y*xv[j].y + wv[i].z*xv[j].z + wv[i].w*xv[j].w;
    }
    // stage p+2 into the buffer just consumed (cur), 2-deep pipeline
    if (pp < 6 && p + 2 < 1287) {
      asm volatile("s_waitcnt lgkmcnt(0)" ::: "memory");
      #pragma unroll
      for (int i = 0; i < 5; ++i) {
        int g = i*64 + lane, v = g >> 3, s4 = (g & 7) ^ (v & 7);
        gload16(Wl + (size_t)(p+2)*1280 + (v*8 + s4)*4, myw + cur*1280 + i*256);
      }
    }
    // write u + accumulate s0 partial
    float* up = u + ((size_t)(bg*1287 + p))*6400 + l*160;
    #pragma unroll
    for (int i = 0; i < 5; ++i) {
      int v = vg*5 + i;
      *(float4*)(up + v*4) = make_float4(acc[i][0], acc[i][1], acc[i][2], acc[i][3]);
      #pragma unroll
      for (int j = 0; j < 4; ++j) s0acc[i][j] += acc[i][j];
    }
    cur ^= 1;
  }
  float* sp = s0part + (size_t)chunk*51200 + l*1280;
  #pragma unroll
  for (int i = 0; i < 5; ++i) {
    int v = vg*5 + i;
    *(float4*)(sp + v*32 + bg*4) =
        make_float4(s0acc[i][0], s0acc[i][1], s0acc[i][2], s0acc[i][3]);
  }
}

// ---------------------------------------------------------------------------
// squash0: s0 [lv][b32] -> v0t [q4][l][v][b4], scaled by 1/40 (uniform c).
// ---------------------------------------------------------------------------
__global__ __launch_bounds__(64) void k_squash0(
    const float* __restrict__ s0, float* __restrict__ v0t)
{
  const int b = blockIdx.x / 40, l = blockIdx.x % 40, t = threadIdx.x;
  float s = 0.f;
  if (t < 40) s = s0[(l*40 + t)*32 + b] * (1.f/40.f);
  float sq = s*s;
  #pragma unroll
  for (int d = 1; d < 64; d <<= 1) sq += __shfl_xor(sq, d);
  float scale = sq > 0.f ? sq / ((1.f + sq) * sqrtf(sq)) : 0.f;
  if (t < 40) v0t[((size_t)(b >> 2)*1600 + l*40 + t)*4 + (b & 3)] = s * scale;
}

__global__ __launch_bounds__(64) void k_squash1(
    const float* __restrict__ sred, float* __restrict__ v1t)
{
  const int b = blockIdx.x / 40, l = blockIdx.x % 40, t = threadIdx.x;
  float s = 0.f;
  size_t off = ((size_t)(b >> 2)*1600 + l*40 + t)*4 + (b & 3);
  if (t < 40) s = sred[off];
  float sq = s*s;
  #pragma unroll
  for (int d = 1; d < 64; d <<= 1) sq += __shfl_xor(sq, d);
  float scale = sq > 0.f ? sq / ((1.f + sq) * sqrtf(sq)) : 0.f;
  if (t < 40) v1t[off] = s * scale;
}

__global__ __launch_bounds__(64) void k_final(
    const float* __restrict__ sred, float* __restrict__ out)
{
  const int b = blockIdx.x / 40, l = blockIdx.x % 40, t = threadIdx.x;
  float s = 0.f;
  if (t < 40) s = sred[((size_t)(b >> 2)*1600 + l*40 + t)*4 + (b & 3)];
  float sq = s*s, ss = s;
  #pragma unroll
  for (int d = 1; d < 64; d <<= 1) { sq += __shfl_xor(sq, d); ss += __shfl_xor(ss, d); }
  float scale = sq > 0.f ? sq / ((1.f + sq) * sqrtf(sq)) : 0.f;
  if (t == 0) out[b*40 + l] = ss * scale;
}

// ---------------------------------------------------------------------------
// k_dot / k_soft / k_sacc: unchanged from R3 (validated, streaming).
// ---------------------------------------------------------------------------
__global__ __launch_bounds__(256) void k_dot(
    const float* __restrict__ u, const float* __restrict__ vprev,
    float* __restrict__ b1g, int pass)
{
  const int tid = blockIdx.x*256 + threadIdx.x;
  if (tid >= 411840) return;
  const int l = tid % 40;
  const int y = tid / 40;
  const int p = y % 1287, q4 = y / 1287;
  const float4* up = (const float4*)(u + (size_t)(q4*1287 + p)*6400 + l*160);
  const float4* vp = (const float4*)(vprev + ((size_t)q4*1600 + l*40)*4);
  float4 d = make_float4(0.f, 0.f, 0.f, 0.f);
  #pragma unroll 8
  for (int v = 0; v < 40; ++v) {
    float4 uu = up[v], vv = vp[v];
    d.x += uu.x*vv.x; d.y += uu.y*vv.y; d.z += uu.z*vv.z; d.w += uu.w*vv.w;
  }
  float4* bp = (float4*)(b1g + (size_t)tid*4);
  if (pass == 2) {
    float4 o = *bp;
    d.x += o.x; d.y += o.y; d.z += o.z; d.w += o.w;
  }
  *bp = d;
}

__global__ __launch_bounds__(256) void k_soft(
    const float* __restrict__ b1g, float* __restrict__ c_g)
{
  const int tid = blockIdx.x*256 + threadIdx.x;
  if (tid >= 41184) return;
  const int b4 = tid & 3, qp = tid >> 2;
  const float* base = b1g + (size_t)qp*160 + b4;
  float e[40];
  float m = -1e30f;
  #pragma unroll
  for (int li = 0; li < 40; ++li) { e[li] = base[li*4]; m = fmaxf(m, e[li]); }
  float Z = 0.f;
  #pragma unroll
  for (int li = 0; li < 40; ++li) { e[li] = expf(e[li] - m); Z += e[li]; }
  float r = 1.f / Z;
  float* cb = c_g + (size_t)qp*160 + b4;
  #pragma unroll
  for (int li = 0; li < 40; ++li) cb[li*4] = e[li] * r;
}

#define PC 10
__global__ __launch_bounds__(320) void k_sacc(
    const float* __restrict__ u, const float* __restrict__ c_g,
    float* __restrict__ spart)
{
  const int q4 = blockIdx.x & 7, chunk = blockIdx.x >> 3;
  const int t = threadIdx.x;
  float4 sreg[5];
  int l4[5];
  #pragma unroll
  for (int k = 0; k < 5; ++k) {
    sreg[k] = make_float4(0.f, 0.f, 0.f, 0.f);
    l4[k] = (k*320 + t) / 40;
  }
  const int p0 = chunk * PC;
  #pragma unroll 2
  for (int pp = 0; pp < PC; ++pp) {
    int p = p0 + pp;
    if (p >= 1287) break;
    const float4* up = (const float4*)(u + (size_t)(q4*1287 + p)*6400);
    const float4* cp = (const float4*)(c_g + (size_t)(q4*1287 + p)*160);
    #pragma unroll
    for (int k = 0; k < 5; ++k) {
      float4 uu = up[k*320 + t];
      float4 cc = cp[l4[k]];
      sreg[k].x += uu.x*cc.x; sreg[k].y += uu.y*cc.y;
      sreg[k].z += uu.z*cc.z; sreg[k].w += uu.w*cc.w;
    }
  }
  float4* sp = (float4*)(spart + ((size_t)chunk*8 + q4)*6400);
  #pragma unroll
  for (int k = 0; k < 5; ++k) sp[k*320 + t] = sreg[k];
}

// sout[w] = sum_{c<n} src[c][w], w < 51200
__global__ __launch_bounds__(256) void k_reduceN(
    const float* __restrict__ src, float* __restrict__ sout, int n)
{
  const int w = blockIdx.x*256 + threadIdx.x;
  float s = 0.f;
  #pragma unroll 4
  for (int c = 0; c < n; ++c) s += src[(size_t)c*51200 + w];
  sout[w] = s;
}

// ---------------------------------------------------------------------------
extern "C" void kernel_launch(void* const* d_in, const int* in_sizes, int n_in,
                              void* d_out, int out_size, void* d_ws, size_t ws_size,
                              hipStream_t stream)
{
  const float* data = (const float*)d_in[0];
  const float* w1   = (const float*)d_in[1];
  const float* w2   = (const float*)d_in[2];
  const float* w3   = (const float*)d_in[3];
  const float* lw   = (const float*)d_in[4];
  const float* bg   = (const float*)d_in[5];
  const float* bb   = (const float*)d_in[6];
  const float* bm   = (const float*)d_in[7];
  const float* bv   = (const float*)d_in[8];
  const float* W    = (const float*)d_in[9];
  float* out = (float*)d_out;

  float* u      = (float*)d_ws;            // 65,894,400
  float* s0     = u + 65894400;            // 51,200
  float* v0t    = s0 + 51200;              // 51,200
  float* v1t    = v0t + 51200;             // 51,200
  float* s1     = v1t + 51200;             // 51,200
  float* xt     = s1 + 51200;              // 1,317,888
  float* big    = xt + 1317888;            // 9,899,520 shared region
  float* s0part = big;                     // [161][51200] (dead after reduce)
  float* b1g    = big;                     // 1,647,360
  float* c_g    = b1g + 1647360;           // 1,647,360
  float* spart  = c_g + 1647360;           // 6,604,800
  // total ~309 MB

  const int KU_LDS = (8192 + 4*2*1280) * 4;  // 73,728 B
  hipFuncSetAttribute((const void*)k_uhat,
                      hipFuncAttributeMaxDynamicSharedMemorySize, KU_LDS);

  k_front<<<256, 256, 0, stream>>>(data, w1, w2, w3, lw, bg, bb, bm, bv, xt);
  k_uhat<<<1610, 256, KU_LDS, stream>>>(W, xt, u, s0part);
  k_reduceN<<<200, 256, 0, stream>>>(s0part, s0, 161);
  k_squash0<<<1280, 64, 0, stream>>>(s0, v0t);

  k_dot<<<1609, 256, 0, stream>>>(u, v0t, b1g, 1);
  k_soft<<<161, 256, 0, stream>>>(b1g, c_g);
  k_sacc<<<1032, 320, 0, stream>>>(u, c_g, spart);
  k_reduceN<<<200, 256, 0, stream>>>(spart, s1, 129);
  k_squash1<<<1280, 64, 0, stream>>>(s1, v1t);

  k_dot<<<1609, 256, 0, stream>>>(u, v1t, b1g, 2);
  k_soft<<<161, 256, 0, stream>>>(b1g, c_g);
  k_sacc<<<1032, 320, 0, stream>>>(u, c_g, spart);
  k_reduceN<<<200, 256, 0, stream>>>(spart, s0, 129);
  k_final<<<1280, 64, 0, stream>>>(s0, out);
}